// Round 3
// baseline (160.152 us; speedup 1.0000x reference)
//
#include <hip/hip_runtime.h>
#include <hip/hip_bf16.h>

// B=8, T=1024, DIM=512, H=8, DK=64, L=32, DH=512, DOUT=512
// qkvb (bf16) layout: [1536][8192], rows {q:0..511,k:512..1023,v:1024..1535}, col = b*1024+t.

typedef short bf16x8 __attribute__((ext_vector_type(8)));
typedef float f32x4 __attribute__((ext_vector_type(4)));

static __device__ __forceinline__ unsigned short f2bf(float f) {
  __hip_bfloat16 h = __float2bfloat16(f);
  return *reinterpret_cast<unsigned short*>(&h);
}
static __device__ __forceinline__ float bf2f(unsigned short u) {
  union { unsigned int i; float f; } c; c.i = ((unsigned int)u) << 16;
  return c.f;
}
static __device__ __forceinline__ void gl_lds16(const unsigned short* g, unsigned short* l) {
  __builtin_amdgcn_global_load_lds((const __attribute__((address_space(1))) unsigned int*)g,
                                   (__attribute__((address_space(3))) unsigned int*)l,
                                   16, 0, 0);
}

// ---------------- prep: cast x/Wqkv/Wout -> bf16  +  PsumT  +  zero ctx ----------------
__global__ __launch_bounds__(256) void prep(const float* __restrict__ x,
                                            const float* __restrict__ wqkv,
                                            const float* __restrict__ wout,
                                            const float* __restrict__ relpos,
                                            unsigned short* __restrict__ xb,
                                            unsigned short* __restrict__ wqkvb,
                                            unsigned short* __restrict__ woutb,
                                            float* __restrict__ PsumT,
                                            float* __restrict__ ctx) {
  const int bx = blockIdx.x;
  if (bx < 5120) {
    int j = bx * 256 + threadIdx.x;   // float4 idx: x 1048576 | wqkv 196608 | wout 65536
    const float* src; unsigned short* dst;
    if (j < 1048576) { src = x; dst = xb; }
    else if (j < 1245184) { j -= 1048576; src = wqkv; dst = wqkvb; }
    else { j -= 1245184; src = wout; dst = woutb; }
    float4 v = ((const float4*)src)[j];
    ushort4 o = {f2bf(v.x), f2bf(v.y), f2bf(v.z), f2bf(v.w)};
    ((ushort4*)dst)[j] = o;
  } else if (bx < 5376) {
    const int idx = bx - 5120;            // 256 blocks: d = idx>>2, t-chunk = idx&3
    const int d = idx >> 2;
    const int t = (idx & 3) * 256 + threadIdx.x;
    float acc = 0.f;
    for (int j = 0; j < 63; ++j) {
      int i = t + j - 31;
      float v = relpos[j * 64 + d];
      if (i >= 0 && i < 1024) acc += v;
    }
    PsumT[d * 1024 + t] = acc;
  } else {
    const int z = bx - 5376;              // 64 blocks zero ctx (atomic accumulator)
    float* base = ctx + (size_t)z * 4096;
    for (int i = threadIdx.x * 4; i < 4096; i += 1024)
      *(float4*)(base + i) = (float4){0.f, 0.f, 0.f, 0.f};
  }
}

// ---------------- gemm_qkv: 256x256 tile, BK=64, 512 threads, 2-phase double-buffered ----
// LDS: per buffer 256 rows x 8 chunks of 16B; chunk c of row stored at position c ^ (row&7).
// Same sync structure as the verified 128^2 version; only geometry scaled.

__global__ __launch_bounds__(512) void gemm_qkv(const unsigned short* __restrict__ A,
                                                const unsigned short* __restrict__ B,
                                                unsigned short* __restrict__ C) {
  __shared__ alignas(16) unsigned short As[2][16384];
  __shared__ alignas(16) unsigned short Bs[2][16384];
  const int tid = threadIdx.x;
  const int wave = tid >> 6, lane = tid & 63;
  const int bm = blockIdx.y * 256, bn = blockIdx.x * 256;
  const int wm = (wave >> 2) * 128, wn = (wave & 3) * 64;   // per-wave 128x64 output
  const int fr = lane & 15, cq = lane >> 4;
  const unsigned short* srcA[4];
  const unsigned short* srcB[4];
#pragma unroll
  for (int j = 0; j < 4; ++j) {
    const int s = tid + j * 512;              // [0,2048): 256 rows x 8 chunks
    const int row = s >> 3, cp = s & 7;
    const int c = cp ^ (row & 7);
    srcA[j] = A + (size_t)(bm + row) * 512 + c * 8;
    srcB[j] = B + (size_t)(bn + row) * 512 + c * 8;
  }
  int offA[8][2], offB[4][2];
#pragma unroll
  for (int i = 0; i < 8; ++i)
#pragma unroll
    for (int ks = 0; ks < 2; ++ks) {
      int ra = wm + i * 16 + fr;
      offA[i][ks] = (ra * 8 + ((ks * 4 + cq) ^ (ra & 7))) * 8;
    }
#pragma unroll
  for (int i = 0; i < 4; ++i)
#pragma unroll
    for (int ks = 0; ks < 2; ++ks) {
      int rb = wn + i * 16 + fr;
      offB[i][ks] = (rb * 8 + ((ks * 4 + cq) ^ (rb & 7))) * 8;
    }
  f32x4 acc[8][4];
#pragma unroll
  for (int i = 0; i < 8; ++i)
#pragma unroll
    for (int j = 0; j < 4; ++j) acc[i][j] = (f32x4){0.f, 0.f, 0.f, 0.f};

  auto stage = [&](int sel, int k0) {
#pragma unroll
    for (int j = 0; j < 4; ++j) {
      gl_lds16(srcA[j] + k0, &As[sel][(wave * 64 + j * 512) * 8]);
      gl_lds16(srcB[j] + k0, &Bs[sel][(wave * 64 + j * 512) * 8]);
    }
  };
  auto compute = [&](int sel) {
#pragma unroll
    for (int ks = 0; ks < 2; ++ks) {
      bf16x8 af[8], bq[4];
#pragma unroll
      for (int mi = 0; mi < 8; ++mi) af[mi] = *(const bf16x8*)&As[sel][offA[mi][ks]];
#pragma unroll
      for (int nj = 0; nj < 4; ++nj) bq[nj] = *(const bf16x8*)&Bs[sel][offB[nj][ks]];
#pragma unroll
      for (int mi = 0; mi < 8; ++mi)
#pragma unroll
        for (int nj = 0; nj < 4; ++nj)
          acc[mi][nj] = __builtin_amdgcn_mfma_f32_16x16x32_bf16(af[mi], bq[nj], acc[mi][nj], 0, 0, 0);
    }
  };

  stage(0, 0);
  __syncthreads();
#pragma unroll
  for (int t = 0; t < 7; ++t) {
    stage((t + 1) & 1, (t + 1) * 64);   // next tile's loads fly during compute
    compute(t & 1);
    __syncthreads();                     // drain my loads + barrier: buf ready, safe to overwrite
  }
  compute(1);

#pragma unroll
  for (int mi = 0; mi < 8; ++mi) {
    const int row0 = bm + wm + mi * 16 + cq * 4;
#pragma unroll
    for (int nj = 0; nj < 4; ++nj) {
      const int col = bn + wn + nj * 16 + fr;
#pragma unroll
      for (int rr = 0; rr < 4; ++rr)
        C[(size_t)(row0 + rr) * 8192 + col] = f2bf(acc[mi][nj][rr]);
    }
  }
}

// ---------------- gemm_out: 64x128 tile -> 512 blocks (full chip) ----------------
__global__ __launch_bounds__(256) void gemm_out(const unsigned short* __restrict__ A,
                                                const unsigned short* __restrict__ B,
                                                const float* __restrict__ bias,
                                                float* __restrict__ out) {
  __shared__ alignas(16) unsigned short As[2][4096];   // 64 x 64
  __shared__ alignas(16) unsigned short Bs[2][8192];   // 128 x 64
  const int tid = threadIdx.x;
  const int wave = tid >> 6, lane = tid & 63;
  const int bm = blockIdx.y * 64, bn = blockIdx.x * 128;
  const int wm = (wave >> 1) * 32, wn = (wave & 1) * 64;
  const int fr = lane & 15, cq = lane >> 4;
  const unsigned short* srcA[2];
  const unsigned short* srcB[4];
#pragma unroll
  for (int j = 0; j < 2; ++j) {
    const int s = tid + j * 256;                  // [0,512): A rows 0..63
    const int row = s >> 3, cp = s & 7;
    const int c = cp ^ (row & 7);
    srcA[j] = A + (size_t)(bm + row) * 512 + c * 8;
  }
#pragma unroll
  for (int j = 0; j < 4; ++j) {
    const int s = tid + j * 256;                  // [0,1024): B rows 0..127
    const int row = s >> 3, cp = s & 7;
    const int c = cp ^ (row & 7);
    srcB[j] = B + (size_t)(bn + row) * 512 + c * 8;
  }
  int offA[2][2], offB[4][2];
#pragma unroll
  for (int i = 0; i < 2; ++i)
#pragma unroll
    for (int ks = 0; ks < 2; ++ks) {
      int ra = wm + i * 16 + fr;
      offA[i][ks] = (ra * 8 + ((ks * 4 + cq) ^ (ra & 7))) * 8;
    }
#pragma unroll
  for (int i = 0; i < 4; ++i)
#pragma unroll
    for (int ks = 0; ks < 2; ++ks) {
      int rb = wn + i * 16 + fr;
      offB[i][ks] = (rb * 8 + ((ks * 4 + cq) ^ (rb & 7))) * 8;
    }
  f32x4 acc[2][4];
#pragma unroll
  for (int i = 0; i < 2; ++i)
#pragma unroll
    for (int j = 0; j < 4; ++j) acc[i][j] = (f32x4){0.f, 0.f, 0.f, 0.f};

  auto stage = [&](int sel, int k0) {
#pragma unroll
    for (int j = 0; j < 2; ++j)
      gl_lds16(srcA[j] + k0, &As[sel][(wave * 64 + j * 256) * 8]);
#pragma unroll
    for (int j = 0; j < 4; ++j)
      gl_lds16(srcB[j] + k0, &Bs[sel][(wave * 64 + j * 256) * 8]);
  };
  auto compute = [&](int sel) {
#pragma unroll
    for (int ks = 0; ks < 2; ++ks) {
      bf16x8 af[2], bq[4];
#pragma unroll
      for (int mi = 0; mi < 2; ++mi) af[mi] = *(const bf16x8*)&As[sel][offA[mi][ks]];
#pragma unroll
      for (int nj = 0; nj < 4; ++nj) bq[nj] = *(const bf16x8*)&Bs[sel][offB[nj][ks]];
#pragma unroll
      for (int mi = 0; mi < 2; ++mi)
#pragma unroll
        for (int nj = 0; nj < 4; ++nj)
          acc[mi][nj] = __builtin_amdgcn_mfma_f32_16x16x32_bf16(af[mi], bq[nj], acc[mi][nj], 0, 0, 0);
    }
  };

  stage(0, 0);
  __syncthreads();
#pragma unroll
  for (int t = 0; t < 7; ++t) {
    stage((t + 1) & 1, (t + 1) * 64);
    compute(t & 1);
    __syncthreads();
  }
  compute(1);

#pragma unroll
  for (int mi = 0; mi < 2; ++mi) {
    const int row0 = bm + wm + mi * 16 + cq * 4;
#pragma unroll
    for (int nj = 0; nj < 4; ++nj) {
      const int col = bn + wn + nj * 16 + fr;   // g = b*1024 + t
      const int b = col >> 10, t = col & 1023;
#pragma unroll
      for (int rr = 0; rr < 4; ++rr)
        out[(size_t)b * 524288 + (size_t)(row0 + rr) * 1024 + t] = acc[mi][nj][rr] + bias[row0 + rr];
    }
  }
}

// ---------------- fused stats: blocks [0,1024) = S+BN partials; [1024,2048) = k logsumexp ----
__global__ __launch_bounds__(256) void stats(const unsigned short* __restrict__ qkv,
                                             const float* __restrict__ PsumT,
                                             float* __restrict__ S,
                                             float* __restrict__ part1,
                                             float* __restrict__ part2,
                                             float* __restrict__ lse) {
  const int bx = blockIdx.x;
  const int tid = threadIdx.x, wave = tid >> 6, lane = tid & 63;
  __shared__ float swave[4][64];
  __shared__ float s_lds[64];
  if (bx < 1024) {
    const int tc = bx & 15, n = bx >> 4;
    const int b = n >> 3, h = n & 7;
    const int t0 = tc * 64;
    const int tg = lane & 7, rg = lane >> 3;
    const unsigned short* qbase = qkv + (size_t)(h * 64) * 8192 + b * 1024 + t0 + tg * 8;
    const float* pbase = PsumT + t0 + tg * 8;
    float acc[8] = {0.f};
#pragma unroll
    for (int i = 0; i < 2; ++i) {
      const int d = wave * 16 + i * 8 + rg;
      bf16x8 qv = *(const bf16x8*)(qbase + (size_t)d * 8192);
      float4 p0 = *(const float4*)(pbase + d * 1024);
      float4 p1 = *(const float4*)(pbase + d * 1024 + 4);
      float p[8] = {p0.x, p0.y, p0.z, p0.w, p1.x, p1.y, p1.z, p1.w};
#pragma unroll
      for (int j = 0; j < 8; ++j) acc[j] = fmaf(bf2f((unsigned short)qv[j]), p[j], acc[j]);
    }
#pragma unroll
    for (int off = 8; off < 64; off <<= 1)
#pragma unroll
      for (int j = 0; j < 8; ++j) acc[j] += __shfl_xor(acc[j], off);
    if (rg == 0) {
#pragma unroll
      for (int j = 0; j < 8; ++j) swave[wave][tg * 8 + j] = acc[j];
    }
    __syncthreads();
    if (tid < 64) {
      float s = swave[0][tid] + swave[1][tid] + swave[2][tid] + swave[3][tid];
      s_lds[tid] = s;
      S[(size_t)n * 1024 + t0 + tid] = s;
    }
    __syncthreads();
    const unsigned short* vbase = qkv + (size_t)(1024 + h * 64) * 8192 + b * 1024 + t0 + tg * 8;
    const int blk = n * 16 + tc;
    float sv[8];
#pragma unroll
    for (int j = 0; j < 8; ++j) sv[j] = s_lds[tg * 8 + j];
#pragma unroll
    for (int i = 0; i < 2; ++i) {
      const int e = wave * 16 + i * 8 + rg;
      bf16x8 vv = *(const bf16x8*)(vbase + (size_t)e * 8192);
      float a1 = 0.f, a2 = 0.f;
#pragma unroll
      for (int j = 0; j < 8; ++j) {
        float val = bf2f((unsigned short)vv[j]) * sv[j];
        a1 += val;
        a2 = fmaf(val, val, a2);
      }
#pragma unroll
      for (int off = 1; off < 8; off <<= 1) {
        a1 += __shfl_xor(a1, off);
        a2 += __shfl_xor(a2, off);
      }
      if (tg == 0) {
        part1[e * 1024 + blk] = a1;
        part2[e * 1024 + blk] = a2;
      }
    }
  } else {
    const int r = (bx - 1024) * 4 + wave;     // 0..4095 = hd*8 + b
    const int hd = r >> 3, b = r & 7;
    const unsigned short* row = qkv + (size_t)(512 + hd) * 8192 + b * 1024 + lane * 16;
    uint4 u0 = *(const uint4*)row;
    uint4 u1 = *(const uint4*)(row + 8);
    const unsigned short* us0 = (const unsigned short*)&u0;
    const unsigned short* us1 = (const unsigned short*)&u1;
    float f[16];
#pragma unroll
    for (int i = 0; i < 8; ++i) { f[i] = bf2f(us0[i]); f[8 + i] = bf2f(us1[i]); }
    float m = f[0];
#pragma unroll
    for (int i = 1; i < 16; ++i) m = fmaxf(m, f[i]);
#pragma unroll
    for (int off = 32; off; off >>= 1) m = fmaxf(m, __shfl_xor(m, off));
    float s = 0.f;
#pragma unroll
    for (int i = 0; i < 16; ++i) s += __expf(f[i] - m);
#pragma unroll
    for (int off = 32; off; off >>= 1) s += __shfl_xor(s, off);
    if (lane == 0) lse[r] = m + __logf(s);
  }
}

// ---------------- context via MFMA (atomic accumulate into ctx) + BN-final blocks ----------------
__global__ __launch_bounds__(256) void context_mfma(const unsigned short* __restrict__ qkv,
                                                    const float* __restrict__ lse,
                                                    float* __restrict__ ctx,
                                                    const float* __restrict__ part1,
                                                    const float* __restrict__ part2,
                                                    const float* __restrict__ gamma,
                                                    const float* __restrict__ beta,
                                                    float* __restrict__ scale,
                                                    float* __restrict__ shift) {
  const int tid = threadIdx.x;
  if (blockIdx.y == 64) {
    // BN-final: 4 blocks x 16 e-channels
    const int el = tid >> 4;                 // 0..15
    const int e = blockIdx.x * 16 + el;
    const int slot = tid & 15;
    float a1 = 0.f, a2 = 0.f;
    const float* p1 = part1 + e * 1024 + slot * 64;
    const float* p2 = part2 + e * 1024 + slot * 64;
#pragma unroll
    for (int j = 0; j < 64; j += 4) {
      float4 u = *(const float4*)(p1 + j);
      float4 w = *(const float4*)(p2 + j);
      a1 += u.x + u.y + u.z + u.w;
      a2 += w.x + w.y + w.z + w.w;
    }
#pragma unroll
    for (int off = 1; off < 16; off <<= 1) {
      a1 += __shfl_xor(a1, off);
      a2 += __shfl_xor(a2, off);
    }
    if (slot == 0) {
      const float cnt = 65536.0f;
      float mu = a1 / cnt;
      float var = a2 / cnt - mu * mu;
      float sc = gamma[e] * rsqrtf(var + 1e-5f);
      scale[e] = sc;
      shift[e] = beta[e] - mu * sc;
    }
    return;
  }
  const int tc = blockIdx.x, n = blockIdx.y;
  const int b = n >> 3, h = n & 7;
  const int wave = tid >> 6, lane = tid & 63;
  __shared__ float ls[64];
  __shared__ float ctx_l[64][68];
  if (tid < 64) ls[tid] = lse[(h * 64 + tid) * 8 + b];
  __syncthreads();
  const int fr = lane & 15, fk = (lane >> 4) * 8;
  const size_t colbase = (size_t)b * 1024 + tc * 256 + wave * 64;
  const unsigned short* kbase = qkv + (size_t)(512 + h * 64) * 8192 + colbase;
  const unsigned short* vbase = qkv + (size_t)(1024 + h * 64) * 8192 + colbase;
  f32x4 acc[4][4];
#pragma unroll
  for (int i = 0; i < 4; ++i)
#pragma unroll
    for (int j = 0; j < 4; ++j) acc[i][j] = (f32x4){0.f, 0.f, 0.f, 0.f};
#pragma unroll
  for (int ks = 0; ks < 2; ++ks) {
    const int tb = ks * 32 + fk;
    bf16x8 aF[4], bF[4];
#pragma unroll
    for (int dt = 0; dt < 4; ++dt) {
      const int row = dt * 16 + fr;
      bf16x8 kv = *(const bf16x8*)(kbase + (size_t)row * 8192 + tb);
      const float lv = ls[row];
      bf16x8 pv;
#pragma unroll
      for (int j = 0; j < 8; ++j)
        pv[j] = (short)f2bf(__expf(bf2f((unsigned short)kv[j]) - lv));
      aF[dt] = pv;
    }
#pragma unroll
    for (int et = 0; et < 4; ++et)
      bF[et] = *(const bf16x8*)(vbase + (size_t)(et * 16 + fr) * 8192 + tb);
#pragma unroll
    for (int dt = 0; dt < 4; ++dt)
#pragma unroll
      for (int et = 0; et < 4; ++et)
        acc[dt][et] = __builtin_amdgcn_mfma_f32_16x16x32_bf16(aF[dt], bF[et], acc[dt][et], 0, 0, 0);
  }
#pragma unroll
  for (int w = 0; w < 4; ++w) {
    if (wave == w) {
#pragma unroll
      for (int dt = 0; dt < 4; ++dt)
#pragma unroll
        for (int et = 0; et < 4; ++et) {
          const int col = et * 16 + fr;
#pragma unroll
          for (int rr = 0; rr < 4; ++rr) {
            const int rw = dt * 16 + (lane >> 4) * 4 + rr;
            if (w == 0) ctx_l[rw][col] = acc[dt][et][rr];
            else ctx_l[rw][col] += acc[dt][et][rr];
          }
        }
    }
    __syncthreads();
  }
  float* outp = ctx + (size_t)n * 4096;
  for (int i = tid; i < 4096; i += 256)
    atomicAdd(outp + i, ctx_l[i >> 6][i & 63]);
}

// ---------------- fused content + BN-combine + transpose -> outT bf16 ----------------
__global__ __launch_bounds__(256) void content_out_t(const unsigned short* __restrict__ qkv,
                                                     const float* __restrict__ ctx,
                                                     const float* __restrict__ S,
                                                     const float* __restrict__ scale,
                                                     const float* __restrict__ shift,
                                                     unsigned short* __restrict__ outT) {
  const int chunk = blockIdx.x, n = blockIdx.y;   // grid (16, 64)
  const int b = n >> 3, h = n & 7;
  const int t0 = chunk * 64;
  __shared__ float cs[4096];
  __shared__ alignas(16) unsigned short T[64][72];
  const float* cp = ctx + (size_t)n * 4096;
  for (int i = threadIdx.x * 4; i < 4096; i += 1024)
    *(float4*)&cs[i] = *(const float4*)&cp[i];
  __syncthreads();
  const int tid = threadIdx.x;
  const int e0 = (tid & 15) * 4;
  const int tq = (tid >> 4) * 4;
  const unsigned short* qbase = qkv + (size_t)(h * 64) * 8192 + b * 1024 + t0 + tq;
  float acc[4][4] = {{0.f}};
  for (int d = 0; d < 64; ++d) {
    float4 cv = *(const float4*)&cs[d * 64 + e0];
    ushort4 qu = *(const ushort4*)(qbase + (size_t)d * 8192);
    float qa[4] = {bf2f(qu.x), bf2f(qu.y), bf2f(qu.z), bf2f(qu.w)};
    float ca[4] = {cv.x, cv.y, cv.z, cv.w};
#pragma unroll
    for (int a = 0; a < 4; ++a)
#pragma unroll
      for (int c = 0; c < 4; ++c)
        acc[a][c] = fmaf(ca[a], qa[c], acc[a][c]);
  }
  float4 svv = *(const float4*)(S + (size_t)n * 1024 + t0 + tq);
  float sa[4] = {svv.x, svv.y, svv.z, svv.w};
  float4 scv = *(const float4*)(scale + e0);
  float4 shv = *(const float4*)(shift + e0);
  float sc[4] = {scv.x, scv.y, scv.z, scv.w};
  float sh[4] = {shv.x, shv.y, shv.z, shv.w};
#pragma unroll
  for (int a = 0; a < 4; ++a) {
    ushort4 vu = *(const ushort4*)(qkv + (size_t)(1024 + h * 64 + e0 + a) * 8192 + b * 1024 + t0 + tq);
    float va[4] = {bf2f(vu.x), bf2f(vu.y), bf2f(vu.z), bf2f(vu.w)};
#pragma unroll
    for (int c = 0; c < 4; ++c)
      T[tq + c][e0 + a] = f2bf(fmaf(va[c] * sa[c], sc[a], acc[a][c] + sh[a]));
  }
  __syncthreads();
  const int tl = tid >> 2, dq = (tid & 3) * 16;
  uint4 r0 = *(uint4*)&T[tl][dq];
  uint4 r1 = *(uint4*)&T[tl][dq + 8];
  unsigned short* op = outT + ((size_t)(b * 1024 + t0 + tl)) * 512 + h * 64 + dq;
  *(uint4*)op = r0;
  *(uint4*)(op + 8) = r1;
}

extern "C" void kernel_launch(void* const* d_in, const int* in_sizes, int n_in,
                              void* d_out, int out_size, void* d_ws, size_t ws_size,
                              hipStream_t stream) {
  const float* x       = (const float*)d_in[0];
  const float* Wqkv    = (const float*)d_in[1];
  const float* Wout    = (const float*)d_in[2];
  const float* bout    = (const float*)d_in[3];
  const float* relpos  = (const float*)d_in[4];
  const float* gamma   = (const float*)d_in[5];
  const float* beta    = (const float*)d_in[6];
  float* out = (float*)d_out;

  float* ws = (float*)d_ws;
  unsigned short* qkvb  = (unsigned short*)ws;             // 1536*8192 bf16
  float* p = ws + 6291456;
  unsigned short* xb    = (unsigned short*)p;  p += 2097152;   // 8192x512 bf16
  unsigned short* wqkvb = (unsigned short*)p;  p += 393216;    // 1536x512 bf16
  unsigned short* woutb = (unsigned short*)p;  p += 131072;    // 512x512 bf16
  float* ctx      = p;  p += 262144;                           // 64 x 4096 (atomic accum)
  float* PsumT    = p;  p += 65536;
  float* S        = p;  p += 65536;
  float* lse      = p;  p += 4096;
  float* part1    = p;  p += 65536;
  float* part2    = p;  p += 65536;
  float* scale    = p;  p += 64;
  float* shift    = p;  p += 64;
  unsigned short* outT = (unsigned short*)p;                   // 8192x512 bf16

  // 0. prep: cast inputs + PsumT + zero ctx
  prep<<<5440, 256, 0, stream>>>(x, Wqkv, Wout, relpos, xb, wqkvb, woutb, PsumT, ctx);
  // 1. qkv (bf16) = Wqkv @ x^T, 256x256 tile BK=64 2-phase double-buffered GEMM
  gemm_qkv<<<dim3(32, 6), 512, 0, stream>>>(wqkvb, xb, qkvb);
  // 2. fused stats: S + BN partials, k-row logsumexp
  stats<<<2048, 256, 0, stream>>>(qkvb, PsumT, S, part1, part2, lse);
  // 3. context via MFMA (atomic accumulate) + BN-final blocks
  context_mfma<<<dim3(4, 65), 256, 0, stream>>>(qkvb, lse, ctx, part1, part2, gamma, beta, scale, shift);
  // 4. fused content + BN-combine + transpose
  content_out_t<<<dim3(16, 64), 256, 0, stream>>>(qkvb, ctx, S, scale, shift, outT);
  // 5. final GEMM: out = Wout @ comb + bout (64x128 tiles, full chip)
  gemm_out<<<dim3(64, 8), 256, 0, stream>>>(woutb, outT, bout, out);
}

// Round 4
// 155.052 us; speedup vs baseline: 1.0329x; 1.0329x over previous
//
#include <hip/hip_runtime.h>
#include <hip/hip_bf16.h>

// B=8, T=1024, DIM=512, H=8, DK=64, L=32, DH=512, DOUT=512
// qkvb (bf16) layout: [1536][8192], rows {q:0..511,k:512..1023,v:1024..1535}, col = b*1024+t.

typedef short bf16x8 __attribute__((ext_vector_type(8)));
typedef float f32x4 __attribute__((ext_vector_type(4)));

static __device__ __forceinline__ unsigned short f2bf(float f) {
  __hip_bfloat16 h = __float2bfloat16(f);
  return *reinterpret_cast<unsigned short*>(&h);
}
static __device__ __forceinline__ float bf2f(unsigned short u) {
  union { unsigned int i; float f; } c; c.i = ((unsigned int)u) << 16;
  return c.f;
}
static __device__ __forceinline__ void gl_lds16(const unsigned short* g, unsigned short* l) {
  __builtin_amdgcn_global_load_lds((const __attribute__((address_space(1))) unsigned int*)g,
                                   (__attribute__((address_space(3))) unsigned int*)l,
                                   16, 0, 0);
}

// ---------------- prep: cast x/Wqkv/Wout -> bf16  +  PsumT ----------------
__global__ __launch_bounds__(256) void prep(const float* __restrict__ x,
                                            const float* __restrict__ wqkv,
                                            const float* __restrict__ wout,
                                            const float* __restrict__ relpos,
                                            unsigned short* __restrict__ xb,
                                            unsigned short* __restrict__ wqkvb,
                                            unsigned short* __restrict__ woutb,
                                            float* __restrict__ PsumT) {
  const int bx = blockIdx.x;
  if (bx < 5120) {
    int j = bx * 256 + threadIdx.x;   // float4 idx: x 1048576 | wqkv 196608 | wout 65536
    const float* src; unsigned short* dst;
    if (j < 1048576) { src = x; dst = xb; }
    else if (j < 1245184) { j -= 1048576; src = wqkv; dst = wqkvb; }
    else { j -= 1245184; src = wout; dst = woutb; }
    float4 v = ((const float4*)src)[j];
    ushort4 o = {f2bf(v.x), f2bf(v.y), f2bf(v.z), f2bf(v.w)};
    ((ushort4*)dst)[j] = o;
  } else {
    const int idx = bx - 5120;            // 256 blocks: d = idx>>2, t-chunk = idx&3
    const int d = idx >> 2;
    const int t = (idx & 3) * 256 + threadIdx.x;
    float acc = 0.f;
    for (int j = 0; j < 63; ++j) {
      int i = t + j - 31;
      float v = relpos[j * 64 + d];
      if (i >= 0 && i < 1024) acc += v;
    }
    PsumT[d * 1024 + t] = acc;
  }
}

// ---------------- gemm_qkv: 128x128 tile BK=64, 2-phase dbuf, transpose epilogue ----------------
// LDS: per buffer 128 rows x 8 chunks of 16B; chunk c of row stored at position c ^ (row&7).

__global__ __launch_bounds__(256) void gemm_qkv(const unsigned short* __restrict__ A,
                                                const unsigned short* __restrict__ B,
                                                unsigned short* __restrict__ C) {
  __shared__ alignas(16) unsigned short smem[32768];   // As[2][8192] | Bs[2][8192]
  unsigned short* As = smem;
  unsigned short* Bs = smem + 16384;
  const int tid = threadIdx.x;
  const int wave = tid >> 6, lane = tid & 63;
  const int bm = blockIdx.y * 128, bn = blockIdx.x * 128;
  const int wm = (wave >> 1) * 64, wn = (wave & 1) * 64;
  const int fr = lane & 15, cq = lane >> 4;
  const unsigned short* srcA[4];
  const unsigned short* srcB[4];
#pragma unroll
  for (int j = 0; j < 4; ++j) {
    const int s = tid + j * 256;
    const int row = s >> 3, cp = s & 7;
    const int c = cp ^ (row & 7);
    srcA[j] = A + (size_t)(bm + row) * 512 + c * 8;
    srcB[j] = B + (size_t)(bn + row) * 512 + c * 8;
  }
  int offA[4][2], offB[4][2];
#pragma unroll
  for (int i = 0; i < 4; ++i)
#pragma unroll
    for (int ks = 0; ks < 2; ++ks) {
      int ra = wm + i * 16 + fr;
      offA[i][ks] = (ra * 8 + ((ks * 4 + cq) ^ (ra & 7))) * 8;
      int rb = wn + i * 16 + fr;
      offB[i][ks] = (rb * 8 + ((ks * 4 + cq) ^ (rb & 7))) * 8;
    }
  f32x4 acc[4][4];
#pragma unroll
  for (int i = 0; i < 4; ++i)
#pragma unroll
    for (int j = 0; j < 4; ++j) acc[i][j] = (f32x4){0.f, 0.f, 0.f, 0.f};

  auto stage = [&](int sel, int k0) {
#pragma unroll
    for (int j = 0; j < 4; ++j) {
      gl_lds16(srcA[j] + k0, As + sel * 8192 + (wave * 64 + j * 256) * 8);
      gl_lds16(srcB[j] + k0, Bs + sel * 8192 + (wave * 64 + j * 256) * 8);
    }
  };
  auto compute = [&](int sel) {
#pragma unroll
    for (int ks = 0; ks < 2; ++ks) {
      bf16x8 af[4], bq[4];
#pragma unroll
      for (int mi = 0; mi < 4; ++mi) af[mi] = *(const bf16x8*)(As + sel * 8192 + offA[mi][ks]);
#pragma unroll
      for (int nj = 0; nj < 4; ++nj) bq[nj] = *(const bf16x8*)(Bs + sel * 8192 + offB[nj][ks]);
#pragma unroll
      for (int mi = 0; mi < 4; ++mi)
#pragma unroll
        for (int nj = 0; nj < 4; ++nj)
          acc[mi][nj] = __builtin_amdgcn_mfma_f32_16x16x32_bf16(af[mi], bq[nj], acc[mi][nj], 0, 0, 0);
    }
  };

  stage(0, 0);
  __syncthreads();
#pragma unroll
  for (int t = 0; t < 7; ++t) {
    stage((t + 1) & 1, (t + 1) * 64);   // next tile's loads fly during compute
    compute(t & 1);
    __syncthreads();                     // drain my loads + barrier: buf ready, safe to overwrite
  }
  compute(1);

  // ---- epilogue: acc -> LDS (swizzled row-major 128x128) -> coalesced stores ----
  __syncthreads();                       // everyone done reading staging buffers
  unsigned short* T = smem;              // 128*128 shorts = 32 KB
#pragma unroll
  for (int mi = 0; mi < 4; ++mi)
#pragma unroll
    for (int nj = 0; nj < 4; ++nj) {
      const int col = wn + nj * 16 + fr;
#pragma unroll
      for (int rr = 0; rr < 4; ++rr) {
        const int row = wm + mi * 16 + cq * 4 + rr;
        T[row * 128 + ((col & 7) | ((((col >> 3) ^ (row & 7))) << 3))] = f2bf(acc[mi][nj][rr]);
      }
    }
  __syncthreads();
#pragma unroll
  for (int it = 0; it < 8; ++it) {
    const int row = it * 16 + (tid >> 4);
    const int cc = tid & 15;
    uint4 v = *(const uint4*)(T + row * 128 + ((cc ^ (row & 7)) * 8));
    *(uint4*)(C + (size_t)(bm + row) * 8192 + bn + cc * 8) = v;
  }
}

// ---------------- gemm_out: 128x128 tile, 2-phase dbuf (R1 measured-best) ----------------
__global__ __launch_bounds__(256) void gemm_out(const unsigned short* __restrict__ A,
                                                const unsigned short* __restrict__ B,
                                                const float* __restrict__ bias,
                                                float* __restrict__ out) {
  __shared__ alignas(16) unsigned short As[2][8192];
  __shared__ alignas(16) unsigned short Bs[2][8192];
  const int tid = threadIdx.x;
  const int wave = tid >> 6, lane = tid & 63;
  const int bm = blockIdx.y * 128, bn = blockIdx.x * 128;
  const int wm = (wave >> 1) * 64, wn = (wave & 1) * 64;
  const int fr = lane & 15, cq = lane >> 4;
  const unsigned short* srcA[4];
  const unsigned short* srcB[4];
#pragma unroll
  for (int j = 0; j < 4; ++j) {
    const int s = tid + j * 256;
    const int row = s >> 3, cp = s & 7;
    const int c = cp ^ (row & 7);
    srcA[j] = A + (size_t)(bm + row) * 512 + c * 8;
    srcB[j] = B + (size_t)(bn + row) * 512 + c * 8;
  }
  int offA[4][2], offB[4][2];
#pragma unroll
  for (int i = 0; i < 4; ++i)
#pragma unroll
    for (int ks = 0; ks < 2; ++ks) {
      int ra = wm + i * 16 + fr;
      offA[i][ks] = (ra * 8 + ((ks * 4 + cq) ^ (ra & 7))) * 8;
      int rb = wn + i * 16 + fr;
      offB[i][ks] = (rb * 8 + ((ks * 4 + cq) ^ (rb & 7))) * 8;
    }
  f32x4 acc[4][4];
#pragma unroll
  for (int i = 0; i < 4; ++i)
#pragma unroll
    for (int j = 0; j < 4; ++j) acc[i][j] = (f32x4){0.f, 0.f, 0.f, 0.f};

  auto stage = [&](int sel, int k0) {
#pragma unroll
    for (int j = 0; j < 4; ++j) {
      gl_lds16(srcA[j] + k0, &As[sel][(wave * 64 + j * 256) * 8]);
      gl_lds16(srcB[j] + k0, &Bs[sel][(wave * 64 + j * 256) * 8]);
    }
  };
  auto compute = [&](int sel) {
#pragma unroll
    for (int ks = 0; ks < 2; ++ks) {
      bf16x8 af[4], bq[4];
#pragma unroll
      for (int mi = 0; mi < 4; ++mi) af[mi] = *(const bf16x8*)&As[sel][offA[mi][ks]];
#pragma unroll
      for (int nj = 0; nj < 4; ++nj) bq[nj] = *(const bf16x8*)&Bs[sel][offB[nj][ks]];
#pragma unroll
      for (int mi = 0; mi < 4; ++mi)
#pragma unroll
        for (int nj = 0; nj < 4; ++nj)
          acc[mi][nj] = __builtin_amdgcn_mfma_f32_16x16x32_bf16(af[mi], bq[nj], acc[mi][nj], 0, 0, 0);
    }
  };

  stage(0, 0);
  __syncthreads();
#pragma unroll
  for (int t = 0; t < 7; ++t) {
    stage((t + 1) & 1, (t + 1) * 64);
    compute(t & 1);
    __syncthreads();
  }
  compute(1);

#pragma unroll
  for (int mi = 0; mi < 4; ++mi) {
    const int row0 = bm + wm + mi * 16 + cq * 4;
#pragma unroll
    for (int nj = 0; nj < 4; ++nj) {
      const int col = bn + wn + nj * 16 + fr;   // g = b*1024 + t
      const int b = col >> 10, t = col & 1023;
#pragma unroll
      for (int rr = 0; rr < 4; ++rr)
        out[(size_t)b * 524288 + (size_t)(row0 + rr) * 1024 + t] = acc[mi][nj][rr] + bias[row0 + rr];
    }
  }
}

// ---------------- fused stats: blocks [0,1024) = S+BN partials; [1024,2048) = k logsumexp ----
__global__ __launch_bounds__(256) void stats(const unsigned short* __restrict__ qkv,
                                             const float* __restrict__ PsumT,
                                             float* __restrict__ S,
                                             float* __restrict__ part1,
                                             float* __restrict__ part2,
                                             float* __restrict__ lse) {
  const int bx = blockIdx.x;
  const int tid = threadIdx.x, wave = tid >> 6, lane = tid & 63;
  __shared__ float swave[4][64];
  __shared__ float s_lds[64];
  if (bx < 1024) {
    const int tc = bx & 15, n = bx >> 4;
    const int b = n >> 3, h = n & 7;
    const int t0 = tc * 64;
    const int tg = lane & 7, rg = lane >> 3;
    const unsigned short* qbase = qkv + (size_t)(h * 64) * 8192 + b * 1024 + t0 + tg * 8;
    const float* pbase = PsumT + t0 + tg * 8;
    float acc[8] = {0.f};
#pragma unroll
    for (int i = 0; i < 2; ++i) {
      const int d = wave * 16 + i * 8 + rg;
      bf16x8 qv = *(const bf16x8*)(qbase + (size_t)d * 8192);
      float4 p0 = *(const float4*)(pbase + d * 1024);
      float4 p1 = *(const float4*)(pbase + d * 1024 + 4);
      float p[8] = {p0.x, p0.y, p0.z, p0.w, p1.x, p1.y, p1.z, p1.w};
#pragma unroll
      for (int j = 0; j < 8; ++j) acc[j] = fmaf(bf2f((unsigned short)qv[j]), p[j], acc[j]);
    }
#pragma unroll
    for (int off = 8; off < 64; off <<= 1)
#pragma unroll
      for (int j = 0; j < 8; ++j) acc[j] += __shfl_xor(acc[j], off);
    if (rg == 0) {
#pragma unroll
      for (int j = 0; j < 8; ++j) swave[wave][tg * 8 + j] = acc[j];
    }
    __syncthreads();
    if (tid < 64) {
      float s = swave[0][tid] + swave[1][tid] + swave[2][tid] + swave[3][tid];
      s_lds[tid] = s;
      S[(size_t)n * 1024 + t0 + tid] = s;
    }
    __syncthreads();
    const unsigned short* vbase = qkv + (size_t)(1024 + h * 64) * 8192 + b * 1024 + t0 + tg * 8;
    const int blk = n * 16 + tc;
    float sv[8];
#pragma unroll
    for (int j = 0; j < 8; ++j) sv[j] = s_lds[tg * 8 + j];
#pragma unroll
    for (int i = 0; i < 2; ++i) {
      const int e = wave * 16 + i * 8 + rg;
      bf16x8 vv = *(const bf16x8*)(vbase + (size_t)e * 8192);
      float a1 = 0.f, a2 = 0.f;
#pragma unroll
      for (int j = 0; j < 8; ++j) {
        float val = bf2f((unsigned short)vv[j]) * sv[j];
        a1 += val;
        a2 = fmaf(val, val, a2);
      }
#pragma unroll
      for (int off = 1; off < 8; off <<= 1) {
        a1 += __shfl_xor(a1, off);
        a2 += __shfl_xor(a2, off);
      }
      if (tg == 0) {
        part1[e * 1024 + blk] = a1;
        part2[e * 1024 + blk] = a2;
      }
    }
  } else {
    const int r = (bx - 1024) * 4 + wave;     // 0..4095 = hd*8 + b
    const int hd = r >> 3, b = r & 7;
    const unsigned short* row = qkv + (size_t)(512 + hd) * 8192 + b * 1024 + lane * 16;
    uint4 u0 = *(const uint4*)row;
    uint4 u1 = *(const uint4*)(row + 8);
    const unsigned short* us0 = (const unsigned short*)&u0;
    const unsigned short* us1 = (const unsigned short*)&u1;
    float f[16];
#pragma unroll
    for (int i = 0; i < 8; ++i) { f[i] = bf2f(us0[i]); f[8 + i] = bf2f(us1[i]); }
    float m = f[0];
#pragma unroll
    for (int i = 1; i < 16; ++i) m = fmaxf(m, f[i]);
#pragma unroll
    for (int off = 32; off; off >>= 1) m = fmaxf(m, __shfl_xor(m, off));
    float s = 0.f;
#pragma unroll
    for (int i = 0; i < 16; ++i) s += __expf(f[i] - m);
#pragma unroll
    for (int off = 32; off; off >>= 1) s += __shfl_xor(s, off);
    if (lane == 0) lse[r] = m + __logf(s);
  }
}

// ---------------- context via MFMA with fused softmax-apply ----------------
__global__ __launch_bounds__(256) void context_mfma(const unsigned short* __restrict__ qkv,
                                                    const float* __restrict__ lse,
                                                    float* __restrict__ ctx_part) {
  const int tc = blockIdx.x, n = blockIdx.y;
  const int b = n >> 3, h = n & 7;
  const int tid = threadIdx.x;
  const int wave = tid >> 6, lane = tid & 63;
  __shared__ float ls[64];
  __shared__ float ctx_l[64][68];
  if (tid < 64) ls[tid] = lse[(h * 64 + tid) * 8 + b];
  __syncthreads();
  const int fr = lane & 15, fk = (lane >> 4) * 8;
  const size_t colbase = (size_t)b * 1024 + tc * 256 + wave * 64;
  const unsigned short* kbase = qkv + (size_t)(512 + h * 64) * 8192 + colbase;
  const unsigned short* vbase = qkv + (size_t)(1024 + h * 64) * 8192 + colbase;
  f32x4 acc[4][4];
#pragma unroll
  for (int i = 0; i < 4; ++i)
#pragma unroll
    for (int j = 0; j < 4; ++j) acc[i][j] = (f32x4){0.f, 0.f, 0.f, 0.f};
#pragma unroll
  for (int ks = 0; ks < 2; ++ks) {
    const int tb = ks * 32 + fk;
    bf16x8 aF[4], bF[4];
#pragma unroll
    for (int dt = 0; dt < 4; ++dt) {
      const int row = dt * 16 + fr;
      bf16x8 kv = *(const bf16x8*)(kbase + (size_t)row * 8192 + tb);
      const float lv = ls[row];
      bf16x8 pv;
#pragma unroll
      for (int j = 0; j < 8; ++j)
        pv[j] = (short)f2bf(__expf(bf2f((unsigned short)kv[j]) - lv));
      aF[dt] = pv;
    }
#pragma unroll
    for (int et = 0; et < 4; ++et)
      bF[et] = *(const bf16x8*)(vbase + (size_t)(et * 16 + fr) * 8192 + tb);
#pragma unroll
    for (int dt = 0; dt < 4; ++dt)
#pragma unroll
      for (int et = 0; et < 4; ++et)
        acc[dt][et] = __builtin_amdgcn_mfma_f32_16x16x32_bf16(aF[dt], bF[et], acc[dt][et], 0, 0, 0);
  }
#pragma unroll
  for (int w = 0; w < 4; ++w) {
    if (wave == w) {
#pragma unroll
      for (int dt = 0; dt < 4; ++dt)
#pragma unroll
        for (int et = 0; et < 4; ++et) {
          const int col = et * 16 + fr;
#pragma unroll
          for (int rr = 0; rr < 4; ++rr) {
            const int rw = dt * 16 + (lane >> 4) * 4 + rr;
            if (w == 0) ctx_l[rw][col] = acc[dt][et][rr];
            else ctx_l[rw][col] += acc[dt][et][rr];
          }
        }
    }
    __syncthreads();
  }
  float* outp = ctx_part + ((size_t)tc * 64 + n) * 4096;
  for (int i = tid * 4; i < 4096; i += 1024) {
    const int rw = i >> 6, cc = i & 63;
    *(float4*)(outp + i) = *(const float4*)&ctx_l[rw][cc];
  }
}

// ---------------- fused reduce: blocks [0,256) ctx partials; [256,320) BN final ----------------
__global__ __launch_bounds__(256) void reduce2(const float* __restrict__ part,
                                               float* __restrict__ ctx,
                                               const float* __restrict__ part1,
                                               const float* __restrict__ part2,
                                               const float* __restrict__ gamma,
                                               const float* __restrict__ beta,
                                               float* __restrict__ scale,
                                               float* __restrict__ shift) {
  const int bx = blockIdx.x;
  const int tid = threadIdx.x;
  if (bx < 256) {
    const int i4 = bx * 256 + tid;
    const float4* p = (const float4*)part;
    float4 a = p[i4], b = p[65536 + i4], c = p[131072 + i4], d = p[196608 + i4];
    float4 s = {a.x + b.x + c.x + d.x, a.y + b.y + c.y + d.y,
                a.z + b.z + c.z + d.z, a.w + b.w + c.w + d.w};
    ((float4*)ctx)[i4] = s;
  } else {
    const int e = bx - 256;
    float a1 = 0.f, a2 = 0.f;
#pragma unroll
    for (int i = 0; i < 4; ++i) {
      a1 += part1[e * 1024 + i * 256 + tid];
      a2 += part2[e * 1024 + i * 256 + tid];
    }
#pragma unroll
    for (int off = 32; off; off >>= 1) {
      a1 += __shfl_down(a1, off);
      a2 += __shfl_down(a2, off);
    }
    __shared__ float r1[4], r2[4];
    const int w = tid >> 6, lane = tid & 63;
    if (lane == 0) { r1[w] = a1; r2[w] = a2; }
    __syncthreads();
    if (tid == 0) {
      float s1 = r1[0] + r1[1] + r1[2] + r1[3];
      float s2 = r2[0] + r2[1] + r2[2] + r2[3];
      const float cnt = 65536.0f;
      float mu = s1 / cnt;
      float var = s2 / cnt - mu * mu;
      float sc = gamma[e] * rsqrtf(var + 1e-5f);
      scale[e] = sc;
      shift[e] = beta[e] - mu * sc;
    }
  }
}

// ---------------- fused content + BN-combine + transpose -> outT bf16 ----------------
__global__ __launch_bounds__(256) void content_out_t(const unsigned short* __restrict__ qkv,
                                                     const float* __restrict__ ctx,
                                                     const float* __restrict__ S,
                                                     const float* __restrict__ scale,
                                                     const float* __restrict__ shift,
                                                     unsigned short* __restrict__ outT) {
  const int chunk = blockIdx.x, n = blockIdx.y;   // grid (16, 64)
  const int b = n >> 3, h = n & 7;
  const int t0 = chunk * 64;
  __shared__ float cs[4096];
  __shared__ alignas(16) unsigned short T[64][72];
  const float* cp = ctx + (size_t)n * 4096;
  for (int i = threadIdx.x * 4; i < 4096; i += 1024)
    *(float4*)&cs[i] = *(const float4*)&cp[i];
  __syncthreads();
  const int tid = threadIdx.x;
  const int e0 = (tid & 15) * 4;
  const int tq = (tid >> 4) * 4;
  const unsigned short* qbase = qkv + (size_t)(h * 64) * 8192 + b * 1024 + t0 + tq;
  float acc[4][4] = {{0.f}};
#pragma unroll 8
  for (int d = 0; d < 64; ++d) {
    float4 cv = *(const float4*)&cs[d * 64 + e0];
    ushort4 qu = *(const ushort4*)(qbase + (size_t)d * 8192);
    float qa[4] = {bf2f(qu.x), bf2f(qu.y), bf2f(qu.z), bf2f(qu.w)};
    float ca[4] = {cv.x, cv.y, cv.z, cv.w};
#pragma unroll
    for (int a = 0; a < 4; ++a)
#pragma unroll
      for (int c = 0; c < 4; ++c)
        acc[a][c] = fmaf(ca[a], qa[c], acc[a][c]);
  }
  float4 svv = *(const float4*)(S + (size_t)n * 1024 + t0 + tq);
  float sa[4] = {svv.x, svv.y, svv.z, svv.w};
  float4 scv = *(const float4*)(scale + e0);
  float4 shv = *(const float4*)(shift + e0);
  float sc[4] = {scv.x, scv.y, scv.z, scv.w};
  float sh[4] = {shv.x, shv.y, shv.z, shv.w};
#pragma unroll
  for (int a = 0; a < 4; ++a) {
    ushort4 vu = *(const ushort4*)(qkv + (size_t)(1024 + h * 64 + e0 + a) * 8192 + b * 1024 + t0 + tq);
    float va[4] = {bf2f(vu.x), bf2f(vu.y), bf2f(vu.z), bf2f(vu.w)};
#pragma unroll
    for (int c = 0; c < 4; ++c)
      T[tq + c][e0 + a] = f2bf(fmaf(va[c] * sa[c], sc[a], acc[a][c] + sh[a]));
  }
  __syncthreads();
  const int tl = tid >> 2, dq = (tid & 3) * 16;
  uint4 r0 = *(uint4*)&T[tl][dq];
  uint4 r1 = *(uint4*)&T[tl][dq + 8];
  unsigned short* op = outT + ((size_t)(b * 1024 + t0 + tl)) * 512 + h * 64 + dq;
  *(uint4*)op = r0;
  *(uint4*)(op + 8) = r1;
}

extern "C" void kernel_launch(void* const* d_in, const int* in_sizes, int n_in,
                              void* d_out, int out_size, void* d_ws, size_t ws_size,
                              hipStream_t stream) {
  const float* x       = (const float*)d_in[0];
  const float* Wqkv    = (const float*)d_in[1];
  const float* Wout    = (const float*)d_in[2];
  const float* bout    = (const float*)d_in[3];
  const float* relpos  = (const float*)d_in[4];
  const float* gamma   = (const float*)d_in[5];
  const float* beta    = (const float*)d_in[6];
  float* out = (float*)d_out;

  float* ws = (float*)d_ws;
  unsigned short* qkvb  = (unsigned short*)ws;             // 1536*8192 bf16
  float* p = ws + 6291456;
  unsigned short* xb    = (unsigned short*)p;  p += 2097152;   // 8192x512 bf16
  unsigned short* wqkvb = (unsigned short*)p;  p += 393216;    // 1536x512 bf16
  unsigned short* woutb = (unsigned short*)p;  p += 131072;    // 512x512 bf16
  float* ctx_part = p;  p += 1048576;                          // 4*64*4096
  float* ctx      = p;  p += 262144;
  float* PsumT    = p;  p += 65536;
  float* S        = p;  p += 65536;
  float* lse      = p;  p += 4096;
  float* part1    = p;  p += 65536;
  float* part2    = p;  p += 65536;
  float* scale    = p;  p += 64;
  float* shift    = p;  p += 64;
  unsigned short* outT = (unsigned short*)p;                   // 8192x512 bf16

  // 0. prep: cast inputs + PsumT
  prep<<<5376, 256, 0, stream>>>(x, Wqkv, Wout, relpos, xb, wqkvb, woutb, PsumT);
  // 1. qkv (bf16) = Wqkv @ x^T, BK=64 2-phase dbuf GEMM + coalesced transpose epilogue
  gemm_qkv<<<dim3(64, 12), 256, 0, stream>>>(wqkvb, xb, qkvb);
  // 2. fused stats: S + BN partials, k-row logsumexp
  stats<<<2048, 256, 0, stream>>>(qkvb, PsumT, S, part1, part2, lse);
  // 3. context via MFMA with fused softmax-apply
  context_mfma<<<dim3(4, 64), 256, 0, stream>>>(qkvb, lse, ctx_part);
  // 4. fused reduce: ctx partials + BN final
  reduce2<<<320, 256, 0, stream>>>(ctx_part, ctx, part1, part2, gamma, beta, scale, shift);
  // 5. fused content + BN-combine + transpose
  content_out_t<<<dim3(16, 64), 256, 0, stream>>>(qkvb, ctx, S, scale, shift, outT);
  // 6. final GEMM: out = Wout @ comb + bout
  gemm_out<<<dim3(64, 4), 256, 0, stream>>>(woutb, outT, bout, out);
}

// Round 6
// 153.527 us; speedup vs baseline: 1.0432x; 1.0099x over previous
//
#include <hip/hip_runtime.h>
#include <hip/hip_bf16.h>

// B=8, T=1024, DIM=512, H=8, DK=64, L=32, DH=512, DOUT=512
// qkvb (bf16) layout: [1536][8192], rows {q:0..511,k:512..1023,v:1024..1535}, col = b*1024+t.

typedef short bf16x8 __attribute__((ext_vector_type(8)));
typedef float f32x4 __attribute__((ext_vector_type(4)));

static __device__ __forceinline__ unsigned short f2bf(float f) {
  __hip_bfloat16 h = __float2bfloat16(f);
  return *reinterpret_cast<unsigned short*>(&h);
}
static __device__ __forceinline__ float bf2f(unsigned short u) {
  union { unsigned int i; float f; } c; c.i = ((unsigned int)u) << 16;
  return c.f;
}
static __device__ __forceinline__ void gl_lds16(const unsigned short* g, unsigned short* l) {
  __builtin_amdgcn_global_load_lds((const __attribute__((address_space(1))) unsigned int*)g,
                                   (__attribute__((address_space(3))) unsigned int*)l,
                                   16, 0, 0);
}

// ---------------- prep: cast x/Wqkv/Wout -> bf16  +  PsumT ----------------
__global__ __launch_bounds__(256) void prep(const float* __restrict__ x,
                                            const float* __restrict__ wqkv,
                                            const float* __restrict__ wout,
                                            const float* __restrict__ relpos,
                                            unsigned short* __restrict__ xb,
                                            unsigned short* __restrict__ wqkvb,
                                            unsigned short* __restrict__ woutb,
                                            float* __restrict__ PsumT) {
  const int bx = blockIdx.x;
  if (bx < 5120) {
    int j = bx * 256 + threadIdx.x;   // float4 idx: x 1048576 | wqkv 196608 | wout 65536
    const float* src; unsigned short* dst;
    if (j < 1048576) { src = x; dst = xb; }
    else if (j < 1245184) { j -= 1048576; src = wqkv; dst = wqkvb; }
    else { j -= 1245184; src = wout; dst = woutb; }
    float4 v = ((const float4*)src)[j];
    ushort4 o = {f2bf(v.x), f2bf(v.y), f2bf(v.z), f2bf(v.w)};
    ((ushort4*)dst)[j] = o;
  } else {
    const int idx = bx - 5120;            // 256 blocks: d = idx>>2, t-chunk = idx&3
    const int d = idx >> 2;
    const int t = (idx & 3) * 256 + threadIdx.x;
    float acc = 0.f;
    for (int j = 0; j < 63; ++j) {
      int i = t + j - 31;
      float v = relpos[j * 64 + d];
      if (i >= 0 && i < 1024) acc += v;
    }
    PsumT[d * 1024 + t] = acc;
  }
}

// ---------------- gemm_qkv: 128x128 tile BK=64, 2-phase dbuf, transpose epilogue ----------------
// LDS: per buffer 128 rows x 8 chunks of 16B; chunk c of row stored at position c ^ (row&7).
// XCD swizzle: each XCD owns bn in [xcd*8, xcd*8+8) for all bm -> its xb working set (1MB)
// + wqkvb (1.5MB) is L2-resident across all 12 bm reuses.

__global__ __launch_bounds__(256) void gemm_qkv(const unsigned short* __restrict__ A,
                                                const unsigned short* __restrict__ B,
                                                unsigned short* __restrict__ C) {
  __shared__ alignas(16) unsigned short smem[32768];   // As[2][8192] | Bs[2][8192]
  unsigned short* As = smem;
  unsigned short* Bs = smem + 16384;
  const int tid = threadIdx.x;
  const int wave = tid >> 6, lane = tid & 63;
  const int flat = blockIdx.y * 64 + blockIdx.x;   // 768 blocks, 96 per XCD
  const int xcd = flat & 7, idx = flat >> 3;
  const int bn = (xcd * 8 + (idx & 7)) * 128;
  const int bm = (idx >> 3) * 128;
  const int wm = (wave >> 1) * 64, wn = (wave & 1) * 64;
  const int fr = lane & 15, cq = lane >> 4;
  const unsigned short* srcA[4];
  const unsigned short* srcB[4];
#pragma unroll
  for (int j = 0; j < 4; ++j) {
    const int s = tid + j * 256;
    const int row = s >> 3, cp = s & 7;
    const int c = cp ^ (row & 7);
    srcA[j] = A + (size_t)(bm + row) * 512 + c * 8;
    srcB[j] = B + (size_t)(bn + row) * 512 + c * 8;
  }
  int offA[4][2], offB[4][2];
#pragma unroll
  for (int i = 0; i < 4; ++i)
#pragma unroll
    for (int ks = 0; ks < 2; ++ks) {
      int ra = wm + i * 16 + fr;
      offA[i][ks] = (ra * 8 + ((ks * 4 + cq) ^ (ra & 7))) * 8;
      int rb = wn + i * 16 + fr;
      offB[i][ks] = (rb * 8 + ((ks * 4 + cq) ^ (rb & 7))) * 8;
    }
  f32x4 acc[4][4];
#pragma unroll
  for (int i = 0; i < 4; ++i)
#pragma unroll
    for (int j = 0; j < 4; ++j) acc[i][j] = (f32x4){0.f, 0.f, 0.f, 0.f};

  auto stage = [&](int sel, int k0) {
#pragma unroll
    for (int j = 0; j < 4; ++j) {
      gl_lds16(srcA[j] + k0, As + sel * 8192 + (wave * 64 + j * 256) * 8);
      gl_lds16(srcB[j] + k0, Bs + sel * 8192 + (wave * 64 + j * 256) * 8);
    }
  };
  auto compute = [&](int sel) {
#pragma unroll
    for (int ks = 0; ks < 2; ++ks) {
      bf16x8 af[4], bq[4];
#pragma unroll
      for (int mi = 0; mi < 4; ++mi) af[mi] = *(const bf16x8*)(As + sel * 8192 + offA[mi][ks]);
#pragma unroll
      for (int nj = 0; nj < 4; ++nj) bq[nj] = *(const bf16x8*)(Bs + sel * 8192 + offB[nj][ks]);
#pragma unroll
      for (int mi = 0; mi < 4; ++mi)
#pragma unroll
        for (int nj = 0; nj < 4; ++nj)
          acc[mi][nj] = __builtin_amdgcn_mfma_f32_16x16x32_bf16(af[mi], bq[nj], acc[mi][nj], 0, 0, 0);
    }
  };

  stage(0, 0);
  __syncthreads();
#pragma unroll
  for (int t = 0; t < 7; ++t) {
    stage((t + 1) & 1, (t + 1) * 64);   // next tile's loads fly during compute
    compute(t & 1);
    __syncthreads();                     // drain my loads + barrier: buf ready, safe to overwrite
  }
  compute(1);

  // ---- epilogue: acc -> LDS (swizzled row-major 128x128) -> coalesced stores ----
  __syncthreads();                       // everyone done reading staging buffers
  unsigned short* T = smem;              // 128*128 shorts = 32 KB
#pragma unroll
  for (int mi = 0; mi < 4; ++mi)
#pragma unroll
    for (int nj = 0; nj < 4; ++nj) {
      const int col = wn + nj * 16 + fr;
#pragma unroll
      for (int rr = 0; rr < 4; ++rr) {
        const int row = wm + mi * 16 + cq * 4 + rr;
        T[row * 128 + ((col & 7) | ((((col >> 3) ^ (row & 7))) << 3))] = f2bf(acc[mi][nj][rr]);
      }
    }
  __syncthreads();
#pragma unroll
  for (int it = 0; it < 8; ++it) {
    const int row = it * 16 + (tid >> 4);
    const int cc = tid & 15;
    uint4 v = *(const uint4*)(T + row * 128 + ((cc ^ (row & 7)) * 8));
    *(uint4*)(C + (size_t)(bm + row) * 8192 + bn + cc * 8) = v;
  }
}

// ---------------- gemm_out: 128x128 tile, 2-phase dbuf, XCD swizzle ----------------
__global__ __launch_bounds__(256) void gemm_out(const unsigned short* __restrict__ A,
                                                const unsigned short* __restrict__ B,
                                                const float* __restrict__ bias,
                                                float* __restrict__ out) {
  __shared__ alignas(16) unsigned short As[2][8192];
  __shared__ alignas(16) unsigned short Bs[2][8192];
  const int tid = threadIdx.x;
  const int wave = tid >> 6, lane = tid & 63;
  const int flat = blockIdx.y * 64 + blockIdx.x;   // 256 blocks, 32 per XCD
  const int xcd = flat & 7, idx = flat >> 3;
  const int bn = (xcd * 8 + (idx & 7)) * 128;
  const int bm = (idx >> 3) * 128;
  const int wm = (wave >> 1) * 64, wn = (wave & 1) * 64;
  const int fr = lane & 15, cq = lane >> 4;
  const unsigned short* srcA[4];
  const unsigned short* srcB[4];
#pragma unroll
  for (int j = 0; j < 4; ++j) {
    const int s = tid + j * 256;
    const int row = s >> 3, cp = s & 7;
    const int c = cp ^ (row & 7);
    srcA[j] = A + (size_t)(bm + row) * 512 + c * 8;
    srcB[j] = B + (size_t)(bn + row) * 512 + c * 8;
  }
  int offA[4][2], offB[4][2];
#pragma unroll
  for (int i = 0; i < 4; ++i)
#pragma unroll
    for (int ks = 0; ks < 2; ++ks) {
      int ra = wm + i * 16 + fr;
      offA[i][ks] = (ra * 8 + ((ks * 4 + cq) ^ (ra & 7))) * 8;
      int rb = wn + i * 16 + fr;
      offB[i][ks] = (rb * 8 + ((ks * 4 + cq) ^ (rb & 7))) * 8;
    }
  f32x4 acc[4][4];
#pragma unroll
  for (int i = 0; i < 4; ++i)
#pragma unroll
    for (int j = 0; j < 4; ++j) acc[i][j] = (f32x4){0.f, 0.f, 0.f, 0.f};

  auto stage = [&](int sel, int k0) {
#pragma unroll
    for (int j = 0; j < 4; ++j) {
      gl_lds16(srcA[j] + k0, &As[sel][(wave * 64 + j * 256) * 8]);
      gl_lds16(srcB[j] + k0, &Bs[sel][(wave * 64 + j * 256) * 8]);
    }
  };
  auto compute = [&](int sel) {
#pragma unroll
    for (int ks = 0; ks < 2; ++ks) {
      bf16x8 af[4], bq[4];
#pragma unroll
      for (int mi = 0; mi < 4; ++mi) af[mi] = *(const bf16x8*)&As[sel][offA[mi][ks]];
#pragma unroll
      for (int nj = 0; nj < 4; ++nj) bq[nj] = *(const bf16x8*)&Bs[sel][offB[nj][ks]];
#pragma unroll
      for (int mi = 0; mi < 4; ++mi)
#pragma unroll
        for (int nj = 0; nj < 4; ++nj)
          acc[mi][nj] = __builtin_amdgcn_mfma_f32_16x16x32_bf16(af[mi], bq[nj], acc[mi][nj], 0, 0, 0);
    }
  };

  stage(0, 0);
  __syncthreads();
#pragma unroll
  for (int t = 0; t < 7; ++t) {
    stage((t + 1) & 1, (t + 1) * 64);
    compute(t & 1);
    __syncthreads();
  }
  compute(1);

#pragma unroll
  for (int mi = 0; mi < 4; ++mi) {
    const int row0 = bm + wm + mi * 16 + cq * 4;
#pragma unroll
    for (int nj = 0; nj < 4; ++nj) {
      const int col = bn + wn + nj * 16 + fr;   // g = b*1024 + t
      const int b = col >> 10, t = col & 1023;
#pragma unroll
      for (int rr = 0; rr < 4; ++rr)
        out[(size_t)b * 524288 + (size_t)(row0 + rr) * 1024 + t] = acc[mi][nj][rr] + bias[row0 + rr];
    }
  }
}

// ---------------- fused stats: blocks [0,1024) = S+BN partials; [1024,2048) = k logsumexp ----
__global__ __launch_bounds__(256) void stats(const unsigned short* __restrict__ qkv,
                                             const float* __restrict__ PsumT,
                                             float* __restrict__ S,
                                             float* __restrict__ part1,
                                             float* __restrict__ part2,
                                             float* __restrict__ lse) {
  const int bx = blockIdx.x;
  const int tid = threadIdx.x, wave = tid >> 6, lane = tid & 63;
  __shared__ float swave[4][64];
  __shared__ float s_lds[64];
  if (bx < 1024) {
    const int tc = bx & 15, n = bx >> 4;
    const int b = n >> 3, h = n & 7;
    const int t0 = tc * 64;
    const int tg = lane & 7, rg = lane >> 3;
    const unsigned short* qbase = qkv + (size_t)(h * 64) * 8192 + b * 1024 + t0 + tg * 8;
    const float* pbase = PsumT + t0 + tg * 8;
    float acc[8] = {0.f};
#pragma unroll
    for (int i = 0; i < 2; ++i) {
      const int d = wave * 16 + i * 8 + rg;
      bf16x8 qv = *(const bf16x8*)(qbase + (size_t)d * 8192);
      float4 p0 = *(const float4*)(pbase + d * 1024);
      float4 p1 = *(const float4*)(pbase + d * 1024 + 4);
      float p[8] = {p0.x, p0.y, p0.z, p0.w, p1.x, p1.y, p1.z, p1.w};
#pragma unroll
      for (int j = 0; j < 8; ++j) acc[j] = fmaf(bf2f((unsigned short)qv[j]), p[j], acc[j]);
    }
#pragma unroll
    for (int off = 8; off < 64; off <<= 1)
#pragma unroll
      for (int j = 0; j < 8; ++j) acc[j] += __shfl_xor(acc[j], off);
    if (rg == 0) {
#pragma unroll
      for (int j = 0; j < 8; ++j) swave[wave][tg * 8 + j] = acc[j];
    }
    __syncthreads();
    if (tid < 64) {
      float s = swave[0][tid] + swave[1][tid] + swave[2][tid] + swave[3][tid];
      s_lds[tid] = s;
      S[(size_t)n * 1024 + t0 + tid] = s;
    }
    __syncthreads();
    const unsigned short* vbase = qkv + (size_t)(1024 + h * 64) * 8192 + b * 1024 + t0 + tg * 8;
    const int blk = n * 16 + tc;
    float sv[8];
#pragma unroll
    for (int j = 0; j < 8; ++j) sv[j] = s_lds[tg * 8 + j];
#pragma unroll
    for (int i = 0; i < 2; ++i) {
      const int e = wave * 16 + i * 8 + rg;
      bf16x8 vv = *(const bf16x8*)(vbase + (size_t)e * 8192);
      float a1 = 0.f, a2 = 0.f;
#pragma unroll
      for (int j = 0; j < 8; ++j) {
        float val = bf2f((unsigned short)vv[j]) * sv[j];
        a1 += val;
        a2 = fmaf(val, val, a2);
      }
#pragma unroll
      for (int off = 1; off < 8; off <<= 1) {
        a1 += __shfl_xor(a1, off);
        a2 += __shfl_xor(a2, off);
      }
      if (tg == 0) {
        part1[e * 1024 + blk] = a1;
        part2[e * 1024 + blk] = a2;
      }
    }
  } else {
    const int r = (bx - 1024) * 4 + wave;     // 0..4095 = hd*8 + b
    const int hd = r >> 3, b = r & 7;
    const unsigned short* row = qkv + (size_t)(512 + hd) * 8192 + b * 1024 + lane * 16;
    uint4 u0 = *(const uint4*)row;
    uint4 u1 = *(const uint4*)(row + 8);
    const unsigned short* us0 = (const unsigned short*)&u0;
    const unsigned short* us1 = (const unsigned short*)&u1;
    float f[16];
#pragma unroll
    for (int i = 0; i < 8; ++i) { f[i] = bf2f(us0[i]); f[8 + i] = bf2f(us1[i]); }
    float m = f[0];
#pragma unroll
    for (int i = 1; i < 16; ++i) m = fmaxf(m, f[i]);
#pragma unroll
    for (int off = 32; off; off >>= 1) m = fmaxf(m, __shfl_xor(m, off));
    float s = 0.f;
#pragma unroll
    for (int i = 0; i < 16; ++i) s += __expf(f[i] - m);
#pragma unroll
    for (int off = 32; off; off >>= 1) s += __shfl_xor(s, off);
    if (lane == 0) lse[r] = m + __logf(s);
  }
}

// ---------------- context via MFMA with fused softmax-apply ----------------
__global__ __launch_bounds__(256) void context_mfma(const unsigned short* __restrict__ qkv,
                                                    const float* __restrict__ lse,
                                                    float* __restrict__ ctx_part) {
  const int tc = blockIdx.x, n = blockIdx.y;
  const int b = n >> 3, h = n & 7;
  const int tid = threadIdx.x;
  const int wave = tid >> 6, lane = tid & 63;
  __shared__ float ls[64];
  __shared__ float ctx_l[64][68];
  if (tid < 64) ls[tid] = lse[(h * 64 + tid) * 8 + b];
  __syncthreads();
  const int fr = lane & 15, fk = (lane >> 4) * 8;
  const size_t colbase = (size_t)b * 1024 + tc * 256 + wave * 64;
  const unsigned short* kbase = qkv + (size_t)(512 + h * 64) * 8192 + colbase;
  const unsigned short* vbase = qkv + (size_t)(1024 + h * 64) * 8192 + colbase;
  f32x4 acc[4][4];
#pragma unroll
  for (int i = 0; i < 4; ++i)
#pragma unroll
    for (int j = 0; j < 4; ++j) acc[i][j] = (f32x4){0.f, 0.f, 0.f, 0.f};
#pragma unroll
  for (int ks = 0; ks < 2; ++ks) {
    const int tb = ks * 32 + fk;
    bf16x8 aF[4], bF[4];
#pragma unroll
    for (int dt = 0; dt < 4; ++dt) {
      const int row = dt * 16 + fr;
      bf16x8 kv = *(const bf16x8*)(kbase + (size_t)row * 8192 + tb);
      const float lv = ls[row];
      bf16x8 pv;
#pragma unroll
      for (int j = 0; j < 8; ++j)
        pv[j] = (short)f2bf(__expf(bf2f((unsigned short)kv[j]) - lv));
      aF[dt] = pv;
    }
#pragma unroll
    for (int et = 0; et < 4; ++et)
      bF[et] = *(const bf16x8*)(vbase + (size_t)(et * 16 + fr) * 8192 + tb);
#pragma unroll
    for (int dt = 0; dt < 4; ++dt)
#pragma unroll
      for (int et = 0; et < 4; ++et)
        acc[dt][et] = __builtin_amdgcn_mfma_f32_16x16x32_bf16(aF[dt], bF[et], acc[dt][et], 0, 0, 0);
  }
#pragma unroll
  for (int w = 0; w < 4; ++w) {
    if (wave == w) {
#pragma unroll
      for (int dt = 0; dt < 4; ++dt)
#pragma unroll
        for (int et = 0; et < 4; ++et) {
          const int col = et * 16 + fr;
#pragma unroll
          for (int rr = 0; rr < 4; ++rr) {
            const int rw = dt * 16 + (lane >> 4) * 4 + rr;
            if (w == 0) ctx_l[rw][col] = acc[dt][et][rr];
            else ctx_l[rw][col] += acc[dt][et][rr];
          }
        }
    }
    __syncthreads();
  }
  float* outp = ctx_part + ((size_t)tc * 64 + n) * 4096;
  for (int i = tid * 4; i < 4096; i += 1024) {
    const int rw = i >> 6, cc = i & 63;
    *(float4*)(outp + i) = *(const float4*)&ctx_l[rw][cc];
  }
}

// ---------------- fused reduce: blocks [0,256) ctx partials; [256,320) BN final ----------------
__global__ __launch_bounds__(256) void reduce2(const float* __restrict__ part,
                                               float* __restrict__ ctx,
                                               const float* __restrict__ part1,
                                               const float* __restrict__ part2,
                                               const float* __restrict__ gamma,
                                               const float* __restrict__ beta,
                                               float* __restrict__ scale,
                                               float* __restrict__ shift) {
  const int bx = blockIdx.x;
  const int tid = threadIdx.x;
  if (bx < 256) {
    const int i4 = bx * 256 + tid;
    const float4* p = (const float4*)part;
    float4 a = p[i4], b = p[65536 + i4], c = p[131072 + i4], d = p[196608 + i4];
    float4 s = {a.x + b.x + c.x + d.x, a.y + b.y + c.y + d.y,
                a.z + b.z + c.z + d.z, a.w + b.w + c.w + d.w};
    ((float4*)ctx)[i4] = s;
  } else {
    const int e = bx - 256;
    float a1 = 0.f, a2 = 0.f;
#pragma unroll
    for (int i = 0; i < 4; ++i) {
      a1 += part1[e * 1024 + i * 256 + tid];
      a2 += part2[e * 1024 + i * 256 + tid];
    }
#pragma unroll
    for (int off = 32; off; off >>= 1) {
      a1 += __shfl_down(a1, off);
      a2 += __shfl_down(a2, off);
    }
    __shared__ float r1[4], r2[4];
    const int w = tid >> 6, lane = tid & 63;
    if (lane == 0) { r1[w] = a1; r2[w] = a2; }
    __syncthreads();
    if (tid == 0) {
      float s1 = r1[0] + r1[1] + r1[2] + r1[3];
      float s2 = r2[0] + r2[1] + r2[2] + r2[3];
      const float cnt = 65536.0f;
      float mu = s1 / cnt;
      float var = s2 / cnt - mu * mu;
      float sc = gamma[e] * rsqrtf(var + 1e-5f);
      scale[e] = sc;
      shift[e] = beta[e] - mu * sc;
    }
  }
}

// ---------------- fused content + BN-combine + transpose -> outT bf16 ----------------
__global__ __launch_bounds__(256) void content_out_t(const unsigned short* __restrict__ qkv,
                                                     const float* __restrict__ ctx,
                                                     const float* __restrict__ S,
                                                     const float* __restrict__ scale,
                                                     const float* __restrict__ shift,
                                                     unsigned short* __restrict__ outT) {
  const int chunk = blockIdx.x, n = blockIdx.y;   // grid (16, 64)
  const int b = n >> 3, h = n & 7;
  const int t0 = chunk * 64;
  __shared__ float cs[4096];
  __shared__ alignas(16) unsigned short T[64][72];
  const float* cp = ctx + (size_t)n * 4096;
  for (int i = threadIdx.x * 4; i < 4096; i += 1024)
    *(float4*)&cs[i] = *(const float4*)&cp[i];
  __syncthreads();
  const int tid = threadIdx.x;
  const int e0 = (tid & 15) * 4;
  const int tq = (tid >> 4) * 4;
  const unsigned short* qbase = qkv + (size_t)(h * 64) * 8192 + b * 1024 + t0 + tq;
  float acc[4][4] = {{0.f}};
#pragma unroll 8
  for (int d = 0; d < 64; ++d) {
    float4 cv = *(const float4*)&cs[d * 64 + e0];
    ushort4 qu = *(const ushort4*)(qbase + (size_t)d * 8192);
    float qa[4] = {bf2f(qu.x), bf2f(qu.y), bf2f(qu.z), bf2f(qu.w)};
    float ca[4] = {cv.x, cv.y, cv.z, cv.w};
#pragma unroll
    for (int a = 0; a < 4; ++a)
#pragma unroll
      for (int c = 0; c < 4; ++c)
        acc[a][c] = fmaf(ca[a], qa[c], acc[a][c]);
  }
  float4 svv = *(const float4*)(S + (size_t)n * 1024 + t0 + tq);
  float sa[4] = {svv.x, svv.y, svv.z, svv.w};
  float4 scv = *(const float4*)(scale + e0);
  float4 shv = *(const float4*)(shift + e0);
  float sc[4] = {scv.x, scv.y, scv.z, scv.w};
  float sh[4] = {shv.x, shv.y, shv.z, shv.w};
#pragma unroll
  for (int a = 0; a < 4; ++a) {
    ushort4 vu = *(const ushort4*)(qkv + (size_t)(1024 + h * 64 + e0 + a) * 8192 + b * 1024 + t0 + tq);
    float va[4] = {bf2f(vu.x), bf2f(vu.y), bf2f(vu.z), bf2f(vu.w)};
#pragma unroll
    for (int c = 0; c < 4; ++c)
      T[tq + c][e0 + a] = f2bf(fmaf(va[c] * sa[c], sc[a], acc[a][c] + sh[a]));
  }
  __syncthreads();
  const int tl = tid >> 2, dq = (tid & 3) * 16;
  uint4 r0 = *(uint4*)&T[tl][dq];
  uint4 r1 = *(uint4*)&T[tl][dq + 8];
  unsigned short* op = outT + ((size_t)(b * 1024 + t0 + tl)) * 512 + h * 64 + dq;
  *(uint4*)op = r0;
  *(uint4*)(op + 8) = r1;
}

extern "C" void kernel_launch(void* const* d_in, const int* in_sizes, int n_in,
                              void* d_out, int out_size, void* d_ws, size_t ws_size,
                              hipStream_t stream) {
  const float* x       = (const float*)d_in[0];
  const float* Wqkv    = (const float*)d_in[1];
  const float* Wout    = (const float*)d_in[2];
  const float* bout    = (const float*)d_in[3];
  const float* relpos  = (const float*)d_in[4];
  const float* gamma   = (const float*)d_in[5];
  const float* beta    = (const float*)d_in[6];
  float* out = (float*)d_out;

  float* ws = (float*)d_ws;
  unsigned short* qkvb  = (unsigned short*)ws;             // 1536*8192 bf16
  float* p = ws + 6291456;
  unsigned short* xb    = (unsigned short*)p;  p += 2097152;   // 8192x512 bf16
  unsigned short* wqkvb = (unsigned short*)p;  p += 393216;    // 1536x512 bf16
  unsigned short* woutb = (unsigned short*)p;  p += 131072;    // 512x512 bf16
  float* ctx_part = p;  p += 1048576;                          // 4*64*4096
  float* ctx      = p;  p += 262144;
  float* PsumT    = p;  p += 65536;
  float* S        = p;  p += 65536;
  float* lse      = p;  p += 4096;
  float* part1    = p;  p += 65536;
  float* part2    = p;  p += 65536;
  float* scale    = p;  p += 64;
  float* shift    = p;  p += 64;
  unsigned short* outT = (unsigned short*)p;                   // 8192x512 bf16

  // 0. prep: cast inputs + PsumT
  prep<<<5376, 256, 0, stream>>>(x, Wqkv, Wout, relpos, xb, wqkvb, woutb, PsumT);
  // 1. qkv (bf16) = Wqkv @ x^T, BK=64 2-phase dbuf GEMM + transpose epilogue + XCD swizzle
  gemm_qkv<<<dim3(64, 12), 256, 0, stream>>>(wqkvb, xb, qkvb);
  // 2. fused stats: S + BN partials, k-row logsumexp
  stats<<<2048, 256, 0, stream>>>(qkvb, PsumT, S, part1, part2, lse);
  // 3. context via MFMA with fused softmax-apply
  context_mfma<<<dim3(4, 64), 256, 0, stream>>>(qkvb, lse, ctx_part);
  // 4. fused reduce: ctx partials + BN final
  reduce2<<<320, 256, 0, stream>>>(ctx_part, ctx, part1, part2, gamma, beta, scale, shift);
  // 5. fused content + BN-combine + transpose
  content_out_t<<<dim3(16, 64), 256, 0, stream>>>(qkvb, ctx, S, scale, shift, outT);
  // 6. final GEMM: out = Wout @ comb + bout (XCD swizzle)
  gemm_out<<<dim3(64, 4), 256, 0, stream>>>(woutb, outT, bout, out);
}